// Round 2
// baseline (17414.342 us; speedup 1.0000x reference)
//
#include <hip/hip_runtime.h>
#include <hip/hip_cooperative_groups.h>

namespace cg = cooperative_groups;

// GRU, B=64, N=1024, T=512.
// Phase 1 (parallel): transpose x, convert weights to bf16 [n][k] layout,
//   precompute P2[t][s][j][b] = (x_t @ {W1z,W1r,W2} + {b1z,b1r,b2}) in bf16.
// Phase 2: ONE persistent cooperative kernel, 256 blocks (1/CU) x 256 thr.
//   Block = (jt, mq): 16 j x 16 b output tile. 4 waves = 4 K-quarters.
//   Gate weights register-resident (96 VGPR/lane, loaded once).
//   h state: bf16 hb[b][k] in global (double-buffered, exchanged via
//   grid.sync()); fp32 h tile for the convex update lives in wave0 registers
//   for all 512 steps. Output written from registers at the end.

#define BATCH 64
#define NN 1024
#define TSTEPS 512

typedef __attribute__((ext_vector_type(8))) short short8;
typedef __attribute__((ext_vector_type(8))) unsigned short u16x8;
typedef __attribute__((ext_vector_type(4))) unsigned short u16x4;
typedef __attribute__((ext_vector_type(4))) float f32x4;

#define MFMA16(a, b, c) __builtin_amdgcn_mfma_f32_16x16x32_bf16((a), (b), (c), 0, 0, 0)

__device__ __forceinline__ unsigned short f2bf(float x) {
  union { float f; unsigned u; } v; v.f = x;
  unsigned u = v.u + 0x7FFFu + ((v.u >> 16) & 1u);   // round-to-nearest-even
  return (unsigned short)(u >> 16);
}
__device__ __forceinline__ float bf2f(unsigned short h) {
  union { unsigned u; float f; } v; v.u = ((unsigned)h) << 16; return v.f;
}

// ---- transpose flow_x [64][1024][512] fp32 -> xT [(t*64+b)][k] bf16 ----
__global__ void trans_x(const float* __restrict__ fx, unsigned short* __restrict__ xT) {
  int bid = blockIdx.x;
  int b   = bid >> 7;          // 0..63
  int rem = bid & 127;
  int kt  = rem >> 3;          // 0..15 (k tiles of 64)
  int tt  = rem & 7;           // 0..7  (t tiles of 64)
  __shared__ float tl[64][65];
  int tx = threadIdx.x & 63;
  int ty = threadIdx.x >> 6;   // 0..3
  const float* src = fx + ((size_t)(b * NN + kt * 64)) * TSTEPS + tt * 64;
#pragma unroll
  for (int i = 0; i < 16; i++) {
    int kr = i * 4 + ty;
    tl[kr][tx] = src[(size_t)kr * TSTEPS + tx];   // coalesced in t
  }
  __syncthreads();
#pragma unroll
  for (int i = 0; i < 16; i++) {
    int tr = i * 4 + ty;
    xT[((size_t)((tt * 64 + tr) * 64 + b)) * NN + kt * 64 + tx] = f2bf(tl[tx][tr]); // coalesced in k
  }
}

// ---- weights fp32 -> wt bf16 [3*1024 rows n=(s,j)][1024 k] ----
__global__ void prep_w(const float* __restrict__ W1, const float* __restrict__ W2,
                       unsigned short* __restrict__ wt) {
  int bid = blockIdx.x;
  int s    = bid >> 8;         // 0..2
  int tile = bid & 255;
  int kt = tile >> 4, jt = tile & 15;
  const float* src = (s < 2) ? W1 : W2;
  int ld = (s < 2) ? 2048 : 1024;
  int co = (s == 1) ? 1024 : 0;
  __shared__ float tl[64][65];
  int tx = threadIdx.x & 63, ty = threadIdx.x >> 6;
#pragma unroll
  for (int i = 0; i < 16; i++) {
    int kr = i * 4 + ty;
    tl[kr][tx] = src[(size_t)(kt * 64 + kr) * ld + co + jt * 64 + tx];
  }
  __syncthreads();
#pragma unroll
  for (int i = 0; i < 16; i++) {
    int jr = i * 4 + ty;
    wt[((size_t)(s * NN + jt * 64 + jr)) * NN + kt * 64 + tx] = f2bf(tl[tx][jr]);
  }
}

// ---- P2[t][s][j][b] = x @ [W1 | W2] + bias, bf16.  C[m=(t,b)][n=(s,j)] ----
__global__ __launch_bounds__(256) void precompute(
    const unsigned short* __restrict__ xT, const unsigned short* __restrict__ wt,
    const float* __restrict__ b1, const float* __restrict__ b2,
    unsigned short* __restrict__ P2) {
  int m0 = (blockIdx.x / 24) * 128;
  int n0 = (blockIdx.x % 24) * 128;
  __shared__ unsigned short As[128 * 40];
  __shared__ unsigned short Bs[128 * 40];
  int tid = threadIdx.x;
  int wave = tid >> 6, lane = tid & 63, q = lane >> 4, li = lane & 15;
  int wm = wave >> 1, wn = wave & 1;
  f32x4 acc[4][4];
#pragma unroll
  for (int a = 0; a < 4; a++)
#pragma unroll
    for (int b = 0; b < 4; b++) acc[a][b] = (f32x4)(0.f);

  for (int kk = 0; kk < 32; ++kk) {
    int K0 = kk * 32;
#pragma unroll
    for (int e = 0; e < 2; e++) {
      int c = tid * 2 + e;
      int row = c >> 2, part = c & 3;
      *(u16x8*)&As[row * 40 + part * 8] =
          *(const u16x8*)&xT[(size_t)(m0 + row) * NN + K0 + part * 8];
      *(u16x8*)&Bs[row * 40 + part * 8] =
          *(const u16x8*)&wt[(size_t)(n0 + row) * NN + K0 + part * 8];
    }
    __syncthreads();
    short8 af[4], bfr[4];
#pragma unroll
    for (int mt = 0; mt < 4; mt++)
      af[mt] = *(const short8*)&As[(wm * 64 + mt * 16 + li) * 40 + q * 8];
#pragma unroll
    for (int nt = 0; nt < 4; nt++)
      bfr[nt] = *(const short8*)&Bs[(wn * 64 + nt * 16 + li) * 40 + q * 8];
#pragma unroll
    for (int mt = 0; mt < 4; mt++)
#pragma unroll
      for (int nt = 0; nt < 4; nt++)
        acc[mt][nt] = MFMA16(af[mt], bfr[nt], acc[mt][nt]);
    __syncthreads();
  }
#pragma unroll
  for (int mt = 0; mt < 4; mt++) {
    int m = m0 + wm * 64 + mt * 16 + q * 4;
    int t = m >> 6, b = m & 63;
#pragma unroll
    for (int nt = 0; nt < 4; nt++) {
      int n = n0 + wn * 64 + nt * 16 + li;
      float bias = (n < 2048) ? b1[n] : b2[n - 2048];
      int s = n >> 10, j = n & 1023;
      f32x4 a = acc[mt][nt];
      u16x4 pk;
      pk.x = f2bf(a.x + bias); pk.y = f2bf(a.y + bias);
      pk.z = f2bf(a.z + bias); pk.w = f2bf(a.w + bias);
      *(u16x4*)&P2[(((size_t)t * 3 + s) * NN + j) * 64 + b] = pk;
    }
  }
}

// ---- persistent scan: all 512 steps in one cooperative kernel ----
__global__ __launch_bounds__(256, 1) void gru_scan(
    unsigned short* __restrict__ hb_a, unsigned short* __restrict__ hb_b,
    const unsigned short* __restrict__ wt, const unsigned short* __restrict__ P2,
    const float* __restrict__ b1, const float* __restrict__ b2,
    float* __restrict__ out) {
  cg::grid_group grid = cg::this_grid();
  int jt = blockIdx.x & 63, mq = blockIdx.x >> 6;
  int j0 = jt * 16, m0 = mq * 16;
  int tid = threadIdx.x, wave = tid >> 6, lane = tid & 63, q = lane >> 4, li = lane & 15;
  int kb = wave * 256;   // this wave's K-quarter

  // --- register-resident gate weights: 24 x short8 = 96 VGPRs ---
  const short8* Bz = (const short8*)&wt[((size_t)(0 * NN + j0 + li)) * NN + kb + q * 8];
  const short8* Br = (const short8*)&wt[((size_t)(1 * NN + j0 + li)) * NN + kb + q * 8];
  const short8* Bv = (const short8*)&wt[((size_t)(2 * NN + j0 + li)) * NN + kb + q * 8];
  short8 wz[8], wr[8], wv[8];
#pragma unroll
  for (int r = 0; r < 8; r++) {
    wz[r] = Bz[r * 4];
    wr[r] = Br[r * 4];
    wv[r] = Bv[r * 4];
  }

  int j = j0 + li;
  int bbase = m0 + q * 4;
  float b1z = b1[j], b1r = b1[NN + j], b2v = b2[j];
  // P2 stream pointers for this lane (only wave0's values are consumed)
  const unsigned short* pz = &P2[((size_t)0 * NN + j) * 64 + bbase];
  const unsigned short* pr = &P2[((size_t)1 * NN + j) * 64 + bbase];
  const unsigned short* pv = &P2[((size_t)2 * NN + j) * 64 + bbase];
  const size_t pstride = (size_t)3 * NN * 64;

  f32x4 hc = (f32x4)(0.f);   // wave0: fp32 h tile, lives in regs all 512 steps
  __shared__ f32x4 red[9][64];

  const unsigned short* hb_in = hb_a;
  unsigned short* hb_out = hb_b;

  for (int t = 0; t < TSTEPS; t++) {
    const short8* Ap = (const short8*)&hb_in[(size_t)(m0 + li) * NN + kb + q * 8];
    u16x4 pz4, pr4, pv4;
    if (wave == 0) {   // issue P2 stream loads early; consumed after reduce
      pz4 = *(const u16x4*)pz;
      pr4 = *(const u16x4*)pr;
      pv4 = *(const u16x4*)pv;
    }
    f32x4 az = (f32x4)(0.f), ar = (f32x4)(0.f), av = (f32x4)(0.f);
#pragma unroll
    for (int r = 0; r < 8; r++) {
      short8 a = Ap[r * 4];
      az = MFMA16(a, wz[r], az);
      ar = MFMA16(a, wr[r], ar);
      av = MFMA16(a, wv[r], av);
    }
    if (wave > 0) {
      red[(wave - 1) * 3 + 0][lane] = az;
      red[(wave - 1) * 3 + 1][lane] = ar;
      red[(wave - 1) * 3 + 2][lane] = av;
    }
    __syncthreads();
    if (wave == 0) {
#pragma unroll
      for (int w = 0; w < 3; w++) {
        az += red[w * 3 + 0][lane];
        ar += red[w * 3 + 1][lane];
        av += red[w * 3 + 2][lane];
      }
#pragma unroll
      for (int reg = 0; reg < 4; reg++) {
        float z = 1.f / (1.f + __expf(-(az[reg] + bf2f(pz4[reg]) + b1z)));
        float r = 1.f / (1.f + __expf(-(ar[reg] + bf2f(pr4[reg]) + b1r)));
        float x = bf2f(pv4[reg]) + r * (av[reg] + b2v);
        float e = __expf(-2.f * fabsf(x));        // overflow-safe tanh
        float th = (1.f - e) / (1.f + e);
        float hh = (x >= 0.f) ? th : -th;
        hc[reg] = z * hc[reg] + (1.f - z) * hh;
      }
      // publish bf16 h tile for next step's A-matrix: hb[b][j]
#pragma unroll
      for (int reg = 0; reg < 4; reg++)
        hb_out[(size_t)(bbase + reg) * NN + j] = f2bf(hc[reg]);
    }
    grid.sync();
    // swap buffers
    const unsigned short* tmp = hb_in;
    hb_in = hb_out;
    hb_out = (unsigned short*)tmp;
    pz += pstride; pr += pstride; pv += pstride;
  }

  if (wave == 0) {   // out[b*N + j] from registers
#pragma unroll
    for (int reg = 0; reg < 4; reg++)
      out[(size_t)(bbase + reg) * NN + j] = hc[reg];
  }
}

extern "C" void kernel_launch(void* const* d_in, const int* in_sizes, int n_in,
                              void* d_out, int out_size, void* d_ws, size_t ws_size,
                              hipStream_t stream) {
  const float* flow_x = (const float*)d_in[0];
  const float* W1 = (const float*)d_in[1];
  const float* b1 = (const float*)d_in[2];
  const float* W2 = (const float*)d_in[3];
  const float* b2 = (const float*)d_in[4];
  float* out = (float*)d_out;
  char* ws = (char*)d_ws;
  size_t off = 0;
  auto take = [&](size_t bytes) -> char* {
    char* p = ws + off;
    off += (bytes + 255) & ~(size_t)255;
    return p;
  };
  unsigned short* wt  = (unsigned short*)take((size_t)3 * 1024 * 1024 * 2);
  unsigned short* xT  = (unsigned short*)take((size_t)32768 * 1024 * 2);
  unsigned short* P2  = (unsigned short*)take((size_t)512 * 3 * 1024 * 64 * 2);
  unsigned short* hba = (unsigned short*)take((size_t)64 * 1024 * 2);
  unsigned short* hbb = (unsigned short*)take((size_t)64 * 1024 * 2);

  if (off > ws_size) {
    hipMemsetAsync(d_out, 0, (size_t)out_size * 4, stream);
    return;
  }

  hipMemsetAsync(hba, 0, (size_t)64 * 1024 * 2, stream);  // h0 = 0

  prep_w<<<768, 256, 0, stream>>>(W1, W2, wt);
  trans_x<<<8192, 256, 0, stream>>>(flow_x, xT);
  precompute<<<6144, 256, 0, stream>>>(xT, wt, b1, b2, P2);

  void* args[] = {&hba, &hbb, &wt, &P2, &b1, &b2, &out};
  hipLaunchCooperativeKernel((const void*)gru_scan, dim3(256), dim3(256),
                             args, 0, stream);
}

// Round 3
// 4020.552 us; speedup vs baseline: 4.3313x; 4.3313x over previous
//
#include <hip/hip_runtime.h>
#include <hip/hip_cooperative_groups.h>

namespace cg = cooperative_groups;

// GRU, B=64, N=1024, T=512.
// Phase 1 (parallel): transpose x, weights -> bf16 [n][k], precompute
//   P2[t][s][j][b] = (x_t @ {W1z,W1r,W2} + bias) in bf16.
// Phase 2: ONE persistent cooperative kernel, 256 blocks (1/CU) x 256 thr.
//   Custom 2-level grid barrier (relaxed agent-scope atomics at LLC; no L2
//   flush). h state exchanged via agent-coherent (sc1) loads/stores only.
//   Gate weights register-resident (96 VGPR/lane). fp32 h tile in wave0 regs.

#define BATCH 64
#define NN 1024
#define TSTEPS 512

typedef __attribute__((ext_vector_type(8))) short short8;
typedef __attribute__((ext_vector_type(8))) unsigned short u16x8;
typedef __attribute__((ext_vector_type(4))) unsigned short u16x4;
typedef __attribute__((ext_vector_type(4))) float f32x4;

#define MFMA16(a, b, c) __builtin_amdgcn_mfma_f32_16x16x32_bf16((a), (b), (c), 0, 0, 0)

__device__ __forceinline__ unsigned short f2bf(float x) {
  union { float f; unsigned u; } v; v.f = x;
  unsigned u = v.u + 0x7FFFu + ((v.u >> 16) & 1u);   // round-to-nearest-even
  return (unsigned short)(u >> 16);
}
__device__ __forceinline__ float bf2f(unsigned short h) {
  union { unsigned u; float f; } v; v.u = ((unsigned)h) << 16; return v.f;
}

// ---- transpose flow_x [64][1024][512] fp32 -> xT [(t*64+b)][k] bf16 ----
__global__ void trans_x(const float* __restrict__ fx, unsigned short* __restrict__ xT) {
  int bid = blockIdx.x;
  int b   = bid >> 7;
  int rem = bid & 127;
  int kt  = rem >> 3;
  int tt  = rem & 7;
  __shared__ float tl[64][65];
  int tx = threadIdx.x & 63;
  int ty = threadIdx.x >> 6;
  const float* src = fx + ((size_t)(b * NN + kt * 64)) * TSTEPS + tt * 64;
#pragma unroll
  for (int i = 0; i < 16; i++) {
    int kr = i * 4 + ty;
    tl[kr][tx] = src[(size_t)kr * TSTEPS + tx];
  }
  __syncthreads();
#pragma unroll
  for (int i = 0; i < 16; i++) {
    int tr = i * 4 + ty;
    xT[((size_t)((tt * 64 + tr) * 64 + b)) * NN + kt * 64 + tx] = f2bf(tl[tx][tr]);
  }
}

// ---- weights fp32 -> wt bf16 [3*1024 rows n=(s,j)][1024 k] ----
__global__ void prep_w(const float* __restrict__ W1, const float* __restrict__ W2,
                       unsigned short* __restrict__ wt) {
  int bid = blockIdx.x;
  int s    = bid >> 8;
  int tile = bid & 255;
  int kt = tile >> 4, jt = tile & 15;
  const float* src = (s < 2) ? W1 : W2;
  int ld = (s < 2) ? 2048 : 1024;
  int co = (s == 1) ? 1024 : 0;
  __shared__ float tl[64][65];
  int tx = threadIdx.x & 63, ty = threadIdx.x >> 6;
#pragma unroll
  for (int i = 0; i < 16; i++) {
    int kr = i * 4 + ty;
    tl[kr][tx] = src[(size_t)(kt * 64 + kr) * ld + co + jt * 64 + tx];
  }
  __syncthreads();
#pragma unroll
  for (int i = 0; i < 16; i++) {
    int jr = i * 4 + ty;
    wt[((size_t)(s * NN + jt * 64 + jr)) * NN + kt * 64 + tx] = f2bf(tl[tx][jr]);
  }
}

// ---- P2[t][s][j][b] = x @ [W1 | W2] + bias, bf16 ----
__global__ __launch_bounds__(256) void precompute(
    const unsigned short* __restrict__ xT, const unsigned short* __restrict__ wt,
    const float* __restrict__ b1, const float* __restrict__ b2,
    unsigned short* __restrict__ P2) {
  int m0 = (blockIdx.x / 24) * 128;
  int n0 = (blockIdx.x % 24) * 128;
  __shared__ unsigned short As[128 * 40];
  __shared__ unsigned short Bs[128 * 40];
  int tid = threadIdx.x;
  int wave = tid >> 6, lane = tid & 63, q = lane >> 4, li = lane & 15;
  int wm = wave >> 1, wn = wave & 1;
  f32x4 acc[4][4];
#pragma unroll
  for (int a = 0; a < 4; a++)
#pragma unroll
    for (int b = 0; b < 4; b++) acc[a][b] = (f32x4)(0.f);

  for (int kk = 0; kk < 32; ++kk) {
    int K0 = kk * 32;
#pragma unroll
    for (int e = 0; e < 2; e++) {
      int c = tid * 2 + e;
      int row = c >> 2, part = c & 3;
      *(u16x8*)&As[row * 40 + part * 8] =
          *(const u16x8*)&xT[(size_t)(m0 + row) * NN + K0 + part * 8];
      *(u16x8*)&Bs[row * 40 + part * 8] =
          *(const u16x8*)&wt[(size_t)(n0 + row) * NN + K0 + part * 8];
    }
    __syncthreads();
    short8 af[4], bfr[4];
#pragma unroll
    for (int mt = 0; mt < 4; mt++)
      af[mt] = *(const short8*)&As[(wm * 64 + mt * 16 + li) * 40 + q * 8];
#pragma unroll
    for (int nt = 0; nt < 4; nt++)
      bfr[nt] = *(const short8*)&Bs[(wn * 64 + nt * 16 + li) * 40 + q * 8];
#pragma unroll
    for (int mt = 0; mt < 4; mt++)
#pragma unroll
      for (int nt = 0; nt < 4; nt++)
        acc[mt][nt] = MFMA16(af[mt], bfr[nt], acc[mt][nt]);
    __syncthreads();
  }
#pragma unroll
  for (int mt = 0; mt < 4; mt++) {
    int m = m0 + wm * 64 + mt * 16 + q * 4;
    int t = m >> 6, b = m & 63;
#pragma unroll
    for (int nt = 0; nt < 4; nt++) {
      int n = n0 + wn * 64 + nt * 16 + li;
      float bias = (n < 2048) ? b1[n] : b2[n - 2048];
      int s = n >> 10, j = n & 1023;
      f32x4 a = acc[mt][nt];
      u16x4 pk;
      pk.x = f2bf(a.x + bias); pk.y = f2bf(a.y + bias);
      pk.z = f2bf(a.z + bias); pk.w = f2bf(a.w + bias);
      *(u16x4*)&P2[(((size_t)t * 3 + s) * NN + j) * 64 + b] = pk;
    }
  }
}

// ---- fast grid barrier: 2-level arrival tree, relaxed agent atomics ----
// bar layout (zero-initialized): cnt[g] at bar[g*64] (g=0..15, 256B apart),
// root at bar[16*64], gen flag at bar[17*64].
__device__ __forceinline__ void grid_barrier(unsigned* bar, int bid, unsigned g) {
  __syncthreads();
  if (threadIdx.x == 0) {
    // all hb stores were issued by THIS wave (wave 0): drain them to LLC
    asm volatile("s_waitcnt vmcnt(0)" ::: "memory");
    unsigned prev = __hip_atomic_fetch_add(&bar[(bid >> 4) * 64], 1u,
                                           __ATOMIC_RELAXED, __HIP_MEMORY_SCOPE_AGENT);
    if ((prev & 15u) == 15u) {                 // last block of this group
      unsigned p2 = __hip_atomic_fetch_add(&bar[16 * 64], 1u,
                                           __ATOMIC_RELAXED, __HIP_MEMORY_SCOPE_AGENT);
      if ((p2 & 15u) == 15u)                   // last group overall
        __hip_atomic_store(&bar[17 * 64], g,
                           __ATOMIC_RELAXED, __HIP_MEMORY_SCOPE_AGENT);
    }
    while (__hip_atomic_load(&bar[17 * 64],
                             __ATOMIC_RELAXED, __HIP_MEMORY_SCOPE_AGENT) < g)
      __builtin_amdgcn_s_sleep(1);
  }
  __syncthreads();
}

// ---- persistent scan ----
__global__ __launch_bounds__(256, 1) void gru_scan(
    unsigned short* __restrict__ hb_a, unsigned short* __restrict__ hb_b,
    const unsigned short* __restrict__ wt, const unsigned short* __restrict__ P2,
    const float* __restrict__ b1, const float* __restrict__ b2,
    float* __restrict__ out, unsigned* __restrict__ bar) {
  int bid = blockIdx.x;
  int jt = bid & 63, mq = bid >> 6;
  int j0 = jt * 16, m0 = mq * 16;
  int tid = threadIdx.x, wave = tid >> 6, lane = tid & 63, q = lane >> 4, li = lane & 15;
  int kb = wave * 256;   // this wave's K-quarter

  // --- register-resident gate weights: 24 x short8 = 96 VGPRs ---
  const short8* Bz = (const short8*)&wt[((size_t)(0 * NN + j0 + li)) * NN + kb + q * 8];
  const short8* Br = (const short8*)&wt[((size_t)(1 * NN + j0 + li)) * NN + kb + q * 8];
  const short8* Bv = (const short8*)&wt[((size_t)(2 * NN + j0 + li)) * NN + kb + q * 8];
  short8 wz[8], wr[8], wv[8];
#pragma unroll
  for (int r = 0; r < 8; r++) {
    wz[r] = Bz[r * 4];
    wr[r] = Br[r * 4];
    wv[r] = Bv[r * 4];
  }

  int j = j0 + li;
  int bbase = m0 + q * 4;
  float b1z = b1[j], b1r = b1[NN + j], b2v = b2[j];
  const unsigned short* pz = &P2[((size_t)0 * NN + j) * 64 + bbase];
  const unsigned short* pr = &P2[((size_t)1 * NN + j) * 64 + bbase];
  const unsigned short* pv = &P2[((size_t)2 * NN + j) * 64 + bbase];
  const size_t pstride = (size_t)3 * NN * 64;

  f32x4 hc = (f32x4)(0.f);   // wave0: fp32 h tile, resident all 512 steps
  __shared__ f32x4 red[9][64];

  const unsigned* hb_in = (const unsigned*)hb_a;
  unsigned* hb_out = (unsigned*)hb_b;
  const size_t abase = ((size_t)(m0 + li) * NN + kb + q * 8) >> 1;  // in u32

  for (int t = 0; t < TSTEPS; t++) {
    u16x4 pz4, pr4, pv4;
    if (wave == 0) {   // P2 stream (plain loads; read-only data)
      pz4 = *(const u16x4*)pz;
      pr4 = *(const u16x4*)pr;
      pv4 = *(const u16x4*)pv;
    }
    // issue ALL coherent A-loads first (pay LLC latency once)
    union { unsigned u[4]; short8 s; } fa[8];
#pragma unroll
    for (int r = 0; r < 8; r++)
#pragma unroll
      for (int e = 0; e < 4; e++)
        fa[r].u[e] = __hip_atomic_load(hb_in + abase + r * 16 + e,
                                       __ATOMIC_RELAXED, __HIP_MEMORY_SCOPE_AGENT);
    f32x4 az = (f32x4)(0.f), ar = (f32x4)(0.f), av = (f32x4)(0.f);
#pragma unroll
    for (int r = 0; r < 8; r++) {
      az = MFMA16(fa[r].s, wz[r], az);
      ar = MFMA16(fa[r].s, wr[r], ar);
      av = MFMA16(fa[r].s, wv[r], av);
    }
    if (wave > 0) {
      red[(wave - 1) * 3 + 0][lane] = az;
      red[(wave - 1) * 3 + 1][lane] = ar;
      red[(wave - 1) * 3 + 2][lane] = av;
    }
    __syncthreads();
    if (wave == 0) {
#pragma unroll
      for (int w = 0; w < 3; w++) {
        az += red[w * 3 + 0][lane];
        ar += red[w * 3 + 1][lane];
        av += red[w * 3 + 2][lane];
      }
#pragma unroll
      for (int reg = 0; reg < 4; reg++) {
        float z = 1.f / (1.f + __expf(-(az[reg] + bf2f(pz4[reg]) + b1z)));
        float r = 1.f / (1.f + __expf(-(ar[reg] + bf2f(pr4[reg]) + b1r)));
        float x = bf2f(pv4[reg]) + r * (av[reg] + b2v);
        float e = __expf(-2.f * fabsf(x));        // overflow-safe tanh
        float th = (1.f - e) / (1.f + e);
        float hh = (x >= 0.f) ? th : -th;
        hc[reg] = z * hc[reg] + (1.f - z) * hh;
      }
      // publish bf16 h tile (hb[b][j]); pack adjacent-j pairs -> u32 stores
#pragma unroll
      for (int reg = 0; reg < 4; reg++) {
        unsigned mine = f2bf(hc[reg]);
        unsigned other = (unsigned)__shfl_xor((int)mine, 1, 64);
        if ((lane & 1) == 0) {
          unsigned packed = mine | (other << 16);
          __hip_atomic_store(&hb_out[(size_t)(bbase + reg) * (NN / 2) + (j >> 1)],
                             packed, __ATOMIC_RELAXED, __HIP_MEMORY_SCOPE_AGENT);
        }
      }
    }
    grid_barrier(bar, bid, (unsigned)t + 1);
    // swap buffers
    const unsigned* tmp = hb_in;
    hb_in = hb_out;
    hb_out = (unsigned*)tmp;
    pz += pstride; pr += pstride; pv += pstride;
  }

  if (wave == 0) {   // out[b*N + j] straight from registers
#pragma unroll
    for (int reg = 0; reg < 4; reg++)
      out[(size_t)(bbase + reg) * NN + j] = hc[reg];
  }
}

extern "C" void kernel_launch(void* const* d_in, const int* in_sizes, int n_in,
                              void* d_out, int out_size, void* d_ws, size_t ws_size,
                              hipStream_t stream) {
  const float* flow_x = (const float*)d_in[0];
  const float* W1 = (const float*)d_in[1];
  const float* b1 = (const float*)d_in[2];
  const float* W2 = (const float*)d_in[3];
  const float* b2 = (const float*)d_in[4];
  float* out = (float*)d_out;
  char* ws = (char*)d_ws;
  size_t off = 0;
  auto take = [&](size_t bytes) -> char* {
    char* p = ws + off;
    off += (bytes + 255) & ~(size_t)255;
    return p;
  };
  unsigned short* wt  = (unsigned short*)take((size_t)3 * 1024 * 1024 * 2);
  unsigned short* xT  = (unsigned short*)take((size_t)32768 * 1024 * 2);
  unsigned short* P2  = (unsigned short*)take((size_t)512 * 3 * 1024 * 64 * 2);
  unsigned short* hba = (unsigned short*)take((size_t)64 * 1024 * 2);
  unsigned short* hbb = (unsigned short*)take((size_t)64 * 1024 * 2);
  unsigned*       bar = (unsigned*)take((size_t)18 * 64 * 4);

  if (off > ws_size) {
    hipMemsetAsync(d_out, 0, (size_t)out_size * 4, stream);
    return;
  }

  hipMemsetAsync(hba, 0, (size_t)64 * 1024 * 2, stream);  // h0 = 0
  hipMemsetAsync(bar, 0, (size_t)18 * 64 * 4, stream);    // barrier counters

  prep_w<<<768, 256, 0, stream>>>(W1, W2, wt);
  trans_x<<<8192, 256, 0, stream>>>(flow_x, xT);
  precompute<<<6144, 256, 0, stream>>>(xT, wt, b1, b2, P2);

  void* args[] = {&hba, &hbb, &wt, &P2, &b1, &b2, &out, &bar};
  hipLaunchCooperativeKernel((const void*)gru_scan, dim3(256), dim3(256),
                             args, 0, stream);
}